// Round 1
// baseline (992.265 us; speedup 1.0000x reference)
//
#include <hip/hip_runtime.h>
#include <cstdint>
#include <cstddef>

#define B_ 8
#define C_ 64
#define N_ 4096
#define O_ 64
#define ROWS_ (B_*N_)          // 32768
#define SPLIT_ 4
#define MSPAN_ (N_/SPLIT_)     // 1024
#define CAP_ 16

typedef unsigned long long u64;
typedef unsigned int u32;

// ---- workspace layout (bytes) ----
// xf   [ROWS][64] f32 : 0          (8 MB)
// sq   [ROWS]     f32 : 8388608    (128 KB)
// keys [ROWS][64] u64 : 8519680    (16 MB)   (reused as h after merge)
// knn  [ROWS][16] i32 : 25296896   (2 MB)
// h    [ROWS][64] f32 : 8519680    (aliases keys; written after merge reads keys)
// h1   [ROWS][64] f32 : 27394048   (8 MB)
// bn   sums/params    : 35782656   (sum[64], sumsq[64], scale[64], shift[64])
#define OFF_XF   0
#define OFF_SQ   8388608
#define OFF_KEYS 8519680
#define OFF_IDX  25296896
#define OFF_H    8519680
#define OFF_H1   27394048
#define OFF_BN   35782656

__device__ __forceinline__ void insert16(u64 kv[16], u64 key) {
  // kv sorted ascending; strict-< keeps earlier (lower idx) first on ties,
  // but keys are unique anyway (idx embedded in low bits).
  if (key < kv[15]) {
#pragma unroll
    for (int j = 15; j > 0; --j) {
      u64 a = kv[j-1], b = kv[j];
      kv[j] = (key < a) ? a : ((key < b) ? key : b);
    }
    kv[0] = (key < kv[0]) ? key : kv[0];
  }
}

// ---------------- K0: zero BN accumulators ----------------
__global__ void k_zero(float* __restrict__ p, int n) {
  int i = blockIdx.x * 256 + threadIdx.x;
  if (i < n) p[i] = 0.f;
}

// ---------------- K1: transpose [B,C,N] -> xf[B,N,C], plus sq ----------------
__global__ __launch_bounds__(256) void k_transpose(const float* __restrict__ x,
                                                   float* __restrict__ xf,
                                                   float* __restrict__ sq) {
  __shared__ float lds[64 * 65];
  const int b  = blockIdx.x >> 6;          // 8 batches
  const int n0 = (blockIdx.x & 63) << 6;   // 64 n-tiles of 64
  const int tid = threadIdx.x;
  const float* xb = x + (size_t)b * C_ * N_;
  {
    const int nn = tid & 63;
    const int c0 = tid >> 6;
#pragma unroll
    for (int i = 0; i < 16; ++i) {
      int c = c0 + i * 4;
      lds[c * 65 + nn] = xb[(size_t)c * N_ + n0 + nn];   // coalesced over n
    }
  }
  __syncthreads();
  {
    const int cc  = tid & 63;
    const int nn0 = tid >> 6;
#pragma unroll
    for (int i = 0; i < 16; ++i) {
      int nn = nn0 + i * 4;
      xf[((size_t)(b * N_ + n0 + nn)) * 64 + cc] = lds[cc * 65 + nn]; // coalesced over c
    }
  }
  if (tid < 64) {
    float s = 0.f;
#pragma unroll
    for (int c = 0; c < 64; ++c) { float v = lds[c * 65 + tid]; s += v * v; }
    sq[b * N_ + n0 + tid] = s;
  }
}

// ---------------- K2: fused distance + partial top-16 ----------------
// grid: 8 b x 16 nblk x 4 split = 512 blocks of 256 threads; thread owns one row.
__global__ __launch_bounds__(256, 2) void k_knn(const float* __restrict__ xf,
                                                const float* __restrict__ sq,
                                                u64* __restrict__ keys) {
  __shared__ u64 buf[256 * CAP_];          // per-lane candidate buffers (32 KB)
  const int bx    = blockIdx.x;
  const int split = bx & (SPLIT_ - 1);
  const int nblk  = (bx >> 2) & 15;
  const int b     = bx >> 6;
  const int tid   = threadIdx.x;
  const int n     = nblk * 256 + tid;
  const int r     = b * N_ + n;
  const float* __restrict__ xfb = xf + (size_t)b * N_ * 64;

  float xr[64];                            // own row features in VGPRs
  {
    const float4* xr4 = (const float4*)(xfb + (size_t)n * 64);
#pragma unroll
    for (int j = 0; j < 16; ++j) {
      float4 v = xr4[j];
      xr[4*j+0] = v.x; xr[4*j+1] = v.y; xr[4*j+2] = v.z; xr[4*j+3] = v.w;
    }
  }
  const float sqn = sq[r];
  const float* __restrict__ sqb = sq + b * N_;

  u64 kv[16];
#pragma unroll
  for (int j = 0; j < 16; ++j) kv[j] = ~0ULL;
  u64 thresh = ~0ULL;
  int cnt = 0;
  u64* mybuf = buf + tid * CAP_;

  const int mbase = split * MSPAN_;
  for (int m = 0; m < MSPAN_; ++m) {
    const float4* mr = (const float4*)(xfb + (size_t)(mbase + m) * 64); // wave-uniform
    float a0 = 0.f, a1 = 0.f, a2 = 0.f, a3 = 0.f;
#pragma unroll
    for (int j = 0; j < 16; j += 4) {
      float4 v0 = mr[j+0];
      float4 v1 = mr[j+1];
      float4 v2 = mr[j+2];
      float4 v3 = mr[j+3];
      a0 += v0.x*xr[4*j+ 0] + v0.y*xr[4*j+ 1] + v0.z*xr[4*j+ 2] + v0.w*xr[4*j+ 3];
      a1 += v1.x*xr[4*j+ 4] + v1.y*xr[4*j+ 5] + v1.z*xr[4*j+ 6] + v1.w*xr[4*j+ 7];
      a2 += v2.x*xr[4*j+ 8] + v2.y*xr[4*j+ 9] + v2.z*xr[4*j+10] + v2.w*xr[4*j+11];
      a3 += v3.x*xr[4*j+12] + v3.y*xr[4*j+13] + v3.z*xr[4*j+14] + v3.w*xr[4*j+15];
    }
    float d = sqn + sqb[mbase + m] - 2.f * ((a0 + a1) + (a2 + a3));
    // orderable key: sign-flip float bits (exact, handles tiny-negative self-dist),
    // idx in low bits => lexicographic (dist, idx) == top_k tie-breaking.
    u32 u = __float_as_uint(d);
    u ^= (u & 0x80000000u) ? 0xFFFFFFFFu : 0x80000000u;
    u64 key = ((u64)u << 32) | (u32)(mbase + m);

    bool push = key < thresh;
    if (push) { mybuf[cnt] = key; cnt++; }
    if (__any(cnt == CAP_)) {              // batch-drain: decouples insert cost from wave-any
      for (int i = 0; i < cnt; ++i) insert16(kv, mybuf[i]);
      cnt = 0;
      thresh = kv[15];
    }
  }
  for (int i = 0; i < cnt; ++i) insert16(kv, mybuf[i]);

  u64* outp = keys + ((size_t)r * SPLIT_ + split) * 16;
#pragma unroll
  for (int j = 0; j < 16; ++j) outp[j] = kv[j];
}

// ---------------- K3: merge 4 partial top-16 -> final 16 indices ----------------
__global__ __launch_bounds__(256) void k_merge(const u64* __restrict__ keys,
                                               int* __restrict__ knn) {
  int r = blockIdx.x * 256 + threadIdx.x;
  u64 kv[16];
#pragma unroll
  for (int j = 0; j < 16; ++j) kv[j] = ~0ULL;
  const u64* in = keys + (size_t)r * 64;
  for (int i = 0; i < 64; ++i) insert16(kv, in[i]);
#pragma unroll
  for (int j = 0; j < 16; ++j) knn[r * 16 + j] = (int)(kv[j] & 0xFFFFu);
}

// ---------------- K4: GIN aggregation: h = (1+eps)*xf + sum_k xf[idx] ----------------
__global__ __launch_bounds__(256) void k_aggr(const float* __restrict__ xf,
                                              const int* __restrict__ knn,
                                              const float* __restrict__ eps_gin,
                                              float* __restrict__ h) {
  const int tid = threadIdx.x;
  const int r = blockIdx.x * 4 + (tid >> 6);   // wave per row
  const int c = tid & 63;
  const int b = r >> 12;
  const float* xfb = xf + (size_t)b * N_ * 64;
  const float eps = eps_gin[0];
  float v = (1.f + eps) * xf[(size_t)r * 64 + c];
  const int* kn = knn + r * 16;
#pragma unroll
  for (int j = 0; j < 16; ++j) {
    int m = kn[j];                              // wave-uniform scalar load
    v += xfb[(size_t)m * 64 + c];               // coalesced 256B row read
  }
  h[(size_t)r * 64 + c] = v;
}

// ---------------- K5: h1 = h @ w1 + b1, plus BN partial sums ----------------
__global__ __launch_bounds__(256) void k_gemm1(const float* __restrict__ h,
                                               const float* __restrict__ w1,
                                               const float* __restrict__ b1,
                                               float* __restrict__ h1,
                                               float* __restrict__ bn_acc) {
  __shared__ float w[64 * 64];
  __shared__ float rs[4][64], rs2[4][64];
  const int tid = threadIdx.x;
#pragma unroll
  for (int i = 0; i < 16; ++i) w[tid + i * 256] = w1[tid + i * 256];
  __syncthreads();
  const int o = tid & 63;
  const int q = tid >> 6;
  const int r0 = blockIdx.x * 64;
  const float bias = b1[o];
  float s = 0.f, s2 = 0.f;
#pragma unroll
  for (int i = 0; i < 16; ++i) {
    int row = r0 + q + i * 4;                   // wave-uniform row
    const float* hr = h + (size_t)row * 64;
    float acc = bias;
#pragma unroll
    for (int c = 0; c < 64; ++c) acc += hr[c] * w[c * 64 + o];
    h1[(size_t)row * 64 + o] = acc;
    s += acc; s2 += acc * acc;
  }
  rs[q][o] = s; rs2[q][o] = s2;
  __syncthreads();
  if (tid < 64) {
    float ts  = rs[0][tid] + rs[1][tid] + rs[2][tid] + rs[3][tid];
    float ts2 = rs2[0][tid] + rs2[1][tid] + rs2[2][tid] + rs2[3][tid];
    atomicAdd(&bn_acc[tid], ts);
    atomicAdd(&bn_acc[64 + tid], ts2);
  }
}

// ---------------- K6: finalize BN -> per-channel scale/shift ----------------
__global__ void k_bnfin(const float* __restrict__ bn_acc,
                        const float* __restrict__ gamma,
                        const float* __restrict__ beta,
                        float* __restrict__ bn_par) {
  int o = threadIdx.x;   // 64 threads
  const float inv = 1.f / (float)ROWS_;
  float mean = bn_acc[o] * inv;
  float var  = bn_acc[64 + o] * inv - mean * mean;
  float sc = gamma[o] * rsqrtf(var + 1e-5f);
  bn_par[o] = sc;
  bn_par[64 + o] = beta[o] - mean * sc;
}

// ---------------- K7: BN apply + GELU(erf) + GEMM2 + transposed store ----------------
__global__ __launch_bounds__(256) void k_final(const float* __restrict__ h1,
                                               const float* __restrict__ bn_par,
                                               const float* __restrict__ w2,
                                               const float* __restrict__ b2,
                                               float* __restrict__ out) {
  __shared__ float w[64 * 64];
  __shared__ float hg[64 * 65];                 // padded: kills stride-64 conflicts
  const int tid = threadIdx.x;
#pragma unroll
  for (int i = 0; i < 16; ++i) w[tid + i * 256] = w2[tid + i * 256];
  const int r0 = blockIdx.x * 64;
  const int b  = r0 >> 12;
  const int n0 = r0 & (N_ - 1);
  const int o = tid & 63;
  const int q = tid >> 6;
  const float sc = bn_par[o], sh = bn_par[64 + o];
#pragma unroll
  for (int i = 0; i < 16; ++i) {
    int rl = q + i * 4;
    float v = h1[(size_t)(r0 + rl) * 64 + o] * sc + sh;
    float g = 0.5f * v * (1.f + erff(v * 0.70710678118654752f));
    hg[rl * 65 + o] = g;
  }
  __syncthreads();
  const int nl = tid & 63;
#pragma unroll
  for (int i = 0; i < 16; ++i) {
    int o2 = q + i * 4;                         // wave-uniform
    float acc = b2[o2];
#pragma unroll
    for (int oo = 0; oo < 64; ++oo) acc += hg[nl * 65 + oo] * w[oo * 64 + o2];
    out[((size_t)(b * 64 + o2)) * N_ + n0 + nl] = acc;  // coalesced over n
  }
}

extern "C" void kernel_launch(void* const* d_in, const int* in_sizes, int n_in,
                              void* d_out, int out_size, void* d_ws, size_t ws_size,
                              hipStream_t stream) {
  const float* x     = (const float*)d_in[0];
  const float* w1    = (const float*)d_in[1];
  const float* b1    = (const float*)d_in[2];
  const float* gamma = (const float*)d_in[3];
  const float* beta  = (const float*)d_in[4];
  const float* w2    = (const float*)d_in[5];
  const float* b2    = (const float*)d_in[6];
  const float* eps_g = (const float*)d_in[7];
  float* out = (float*)d_out;

  char* ws = (char*)d_ws;
  float* xf   = (float*)(ws + OFF_XF);
  float* sq   = (float*)(ws + OFF_SQ);
  u64*   keys = (u64*)  (ws + OFF_KEYS);
  int*   knn  = (int*)  (ws + OFF_IDX);
  float* h    = (float*)(ws + OFF_H);     // aliases keys (safe: merge precedes aggr)
  float* h1   = (float*)(ws + OFF_H1);
  float* bn_acc = (float*)(ws + OFF_BN);       // sum[64], sumsq[64]
  float* bn_par = (float*)(ws + OFF_BN + 512); // scale[64], shift[64]

  k_zero<<<1, 256, 0, stream>>>(bn_acc, 128);
  k_transpose<<<512, 256, 0, stream>>>(x, xf, sq);
  k_knn<<<512, 256, 0, stream>>>(xf, sq, keys);
  k_merge<<<ROWS_ / 256, 256, 0, stream>>>(keys, knn);
  k_aggr<<<ROWS_ / 4, 256, 0, stream>>>(xf, knn, eps_g, h);
  k_gemm1<<<ROWS_ / 64, 256, 0, stream>>>(h, w1, b1, h1, bn_acc);
  k_bnfin<<<1, 64, 0, stream>>>(bn_acc, gamma, beta, bn_par);
  k_final<<<ROWS_ / 64, 256, 0, stream>>>(h1, bn_par, w2, b2, out);
}

// Round 2
// 878.191 us; speedup vs baseline: 1.1299x; 1.1299x over previous
//
#include <hip/hip_runtime.h>
#include <cstdint>
#include <cstddef>

#define B_ 8
#define C_ 64
#define N_ 4096
#define O_ 64
#define ROWS_ (B_*N_)          // 32768
#define SPLIT_ 8
#define MSPAN_ (N_/SPLIT_)     // 512
#define CAP_ 16
#define BUFSTRIDE_ 17          // u64 stride: lane i -> bank 2i mod 32 (2-way, free)

typedef unsigned long long u64;
typedef unsigned int u32;
typedef unsigned short u16;

// ---- workspace layout (bytes) ----
// xf   [ROWS][64] f32 : 0            (8 MB)
// sq   [ROWS]     f32 : 8388608      (128 KB)
// kd   [ROWS][128] u32: 8519680      (16 MB)  dist keys per split
// ki   [ROWS][128] u16: 25296896     (8 MB)   idx per split
// knn  [ROWS][16] i32 : 33685504     (2 MB)
// -- after k_merge, kd/ki are dead; aliased: --
// h    [ROWS][64] f32 : 8519680      (8 MB)
// h1   [ROWS][64] f32 : 16908288     (8 MB)
// bn   sums/params    : 25296896     (1 KB)
#define OFF_XF   0
#define OFF_SQ   8388608
#define OFF_KD   8519680
#define OFF_KI   25296896
#define OFF_IDX  33685504
#define OFF_H    8519680
#define OFF_H1   16908288
#define OFF_BN   25296896

__device__ __forceinline__ void insert16(u64 kv[16], u64 key) {
  if (key < kv[15]) {
#pragma unroll
    for (int j = 15; j > 0; --j) {
      u64 a = kv[j-1], b = kv[j];
      kv[j] = (key < a) ? a : ((key < b) ? key : b);
    }
    kv[0] = (key < kv[0]) ? key : kv[0];
  }
}

// ---------------- K0: zero BN accumulators ----------------
__global__ void k_zero(float* __restrict__ p, int n) {
  int i = blockIdx.x * 256 + threadIdx.x;
  if (i < n) p[i] = 0.f;
}

// ---------------- K1: transpose [B,C,N] -> xf[B,N,C], plus sq ----------------
__global__ __launch_bounds__(256) void k_transpose(const float* __restrict__ x,
                                                   float* __restrict__ xf,
                                                   float* __restrict__ sq) {
  __shared__ float lds[64 * 65];
  const int b  = blockIdx.x >> 6;          // 8 batches
  const int n0 = (blockIdx.x & 63) << 6;   // 64 n-tiles of 64
  const int tid = threadIdx.x;
  const float* xb = x + (size_t)b * C_ * N_;
  {
    const int nn = tid & 63;
    const int c0 = tid >> 6;
#pragma unroll
    for (int i = 0; i < 16; ++i) {
      int c = c0 + i * 4;
      lds[c * 65 + nn] = xb[(size_t)c * N_ + n0 + nn];   // coalesced over n
    }
  }
  __syncthreads();
  {
    const int cc  = tid & 63;
    const int nn0 = tid >> 6;
#pragma unroll
    for (int i = 0; i < 16; ++i) {
      int nn = nn0 + i * 4;
      xf[((size_t)(b * N_ + n0 + nn)) * 64 + cc] = lds[cc * 65 + nn]; // coalesced over c
    }
  }
  if (tid < 64) {
    float s = 0.f;
#pragma unroll
    for (int c = 0; c < 64; ++c) { float v = lds[c * 65 + tid]; s += v * v; }
    sq[b * N_ + n0 + tid] = s;
  }
}

// ---------------- K2: fused distance + partial top-16 ----------------
// grid: 8 b x 16 nblk x 8 split = 1024 blocks of 256 threads; thread owns one row.
__global__ __launch_bounds__(256, 4) void k_knn(const float* __restrict__ xf,
                                                const float* __restrict__ sq,
                                                u32* __restrict__ kd,
                                                u16* __restrict__ ki) {
  __shared__ u64 buf[256 * BUFSTRIDE_];    // padded per-lane candidate buffers (34 KB)
  const int bx    = blockIdx.x;
  const int split = bx & (SPLIT_ - 1);
  const int nblk  = (bx >> 3) & 15;
  const int b     = bx >> 7;
  const int tid   = threadIdx.x;
  const int n     = nblk * 256 + tid;
  const int r     = b * N_ + n;
  const float* __restrict__ xfb = xf + (size_t)b * N_ * 64;

  // own-row features in 16 explicit float4s (no private array -> stays in VGPRs)
  const float4* xr4 = (const float4*)(xfb + (size_t)n * 64);
  float4 x0 = xr4[0],  x1 = xr4[1],  x2 = xr4[2],  x3 = xr4[3];
  float4 x4 = xr4[4],  x5 = xr4[5],  x6 = xr4[6],  x7 = xr4[7];
  float4 x8 = xr4[8],  x9 = xr4[9],  x10 = xr4[10], x11 = xr4[11];
  float4 x12 = xr4[12], x13 = xr4[13], x14 = xr4[14], x15 = xr4[15];

  const float sqn = sq[r];
  const float* __restrict__ sqb = sq + b * N_;

  u64 kv[16];
#pragma unroll
  for (int j = 0; j < 16; ++j) kv[j] = ~0ULL;
  u64 thresh = ~0ULL;
  int cnt = 0;
  u64* mybuf = buf + tid * BUFSTRIDE_;

  const int mbase = split * MSPAN_;
  for (int m = 0; m < MSPAN_; ++m) {
    const float4* mr = (const float4*)(xfb + (size_t)(mbase + m) * 64); // wave-uniform
    float a0 = 0.f, a1 = 0.f, a2 = 0.f, a3 = 0.f;
    {
      float4 v0 = mr[0],  v1 = mr[1],  v2 = mr[2],  v3 = mr[3];
      a0 += v0.x*x0.x + v0.y*x0.y + v0.z*x0.z + v0.w*x0.w;
      a1 += v1.x*x1.x + v1.y*x1.y + v1.z*x1.z + v1.w*x1.w;
      a2 += v2.x*x2.x + v2.y*x2.y + v2.z*x2.z + v2.w*x2.w;
      a3 += v3.x*x3.x + v3.y*x3.y + v3.z*x3.z + v3.w*x3.w;
    }
    {
      float4 v0 = mr[4],  v1 = mr[5],  v2 = mr[6],  v3 = mr[7];
      a0 += v0.x*x4.x + v0.y*x4.y + v0.z*x4.z + v0.w*x4.w;
      a1 += v1.x*x5.x + v1.y*x5.y + v1.z*x5.z + v1.w*x5.w;
      a2 += v2.x*x6.x + v2.y*x6.y + v2.z*x6.z + v2.w*x6.w;
      a3 += v3.x*x7.x + v3.y*x7.y + v3.z*x7.z + v3.w*x7.w;
    }
    {
      float4 v0 = mr[8],  v1 = mr[9],  v2 = mr[10], v3 = mr[11];
      a0 += v0.x*x8.x + v0.y*x8.y + v0.z*x8.z + v0.w*x8.w;
      a1 += v1.x*x9.x + v1.y*x9.y + v1.z*x9.z + v1.w*x9.w;
      a2 += v2.x*x10.x + v2.y*x10.y + v2.z*x10.z + v2.w*x10.w;
      a3 += v3.x*x11.x + v3.y*x11.y + v3.z*x11.z + v3.w*x11.w;
    }
    {
      float4 v0 = mr[12], v1 = mr[13], v2 = mr[14], v3 = mr[15];
      a0 += v0.x*x12.x + v0.y*x12.y + v0.z*x12.z + v0.w*x12.w;
      a1 += v1.x*x13.x + v1.y*x13.y + v1.z*x13.z + v1.w*x13.w;
      a2 += v2.x*x14.x + v2.y*x14.y + v2.z*x14.z + v2.w*x14.w;
      a3 += v3.x*x15.x + v3.y*x15.y + v3.z*x15.z + v3.w*x15.w;
    }
    float d = sqn + sqb[mbase + m] - 2.f * ((a0 + a1) + (a2 + a3));
    // orderable key: sign-flip float bits; idx in low bits => (dist, idx) lexicographic
    u32 u = __float_as_uint(d);
    u ^= (u & 0x80000000u) ? 0xFFFFFFFFu : 0x80000000u;
    u64 key = ((u64)u << 32) | (u32)(mbase + m);

    bool push = key < thresh;
    if (push) { mybuf[cnt] = key; cnt++; }
    if (__any(cnt == CAP_)) {              // batch-drain
      for (int i = 0; i < cnt; ++i) insert16(kv, mybuf[i]);
      cnt = 0;
      thresh = kv[15];
    }
  }
  for (int i = 0; i < cnt; ++i) insert16(kv, mybuf[i]);

  u32* dp = kd + ((size_t)r * SPLIT_ + split) * 16;
  u16* ip = ki + ((size_t)r * SPLIT_ + split) * 16;
#pragma unroll
  for (int j = 0; j < 16; ++j) {
    dp[j] = (u32)(kv[j] >> 32);
    ip[j] = (u16)(kv[j] & 0xFFFFu);
  }
}

// ---------------- K3: merge 8 partial top-16 -> final 16 indices ----------------
__global__ __launch_bounds__(256) void k_merge(const u32* __restrict__ kd,
                                               const u16* __restrict__ ki,
                                               int* __restrict__ knn) {
  int r = blockIdx.x * 256 + threadIdx.x;
  u64 kv[16];
#pragma unroll
  for (int j = 0; j < 16; ++j) kv[j] = ~0ULL;
  const u32* dp = kd + (size_t)r * (SPLIT_ * 16);
  const u16* ip = ki + (size_t)r * (SPLIT_ * 16);
  for (int i = 0; i < SPLIT_ * 16; ++i) {
    u64 key = ((u64)dp[i] << 32) | ip[i];
    insert16(kv, key);
  }
#pragma unroll
  for (int j = 0; j < 16; ++j) knn[r * 16 + j] = (int)(kv[j] & 0xFFFFu);
}

// ---------------- K4: GIN aggregation: h = (1+eps)*xf + sum_k xf[idx] ----------------
__global__ __launch_bounds__(256) void k_aggr(const float* __restrict__ xf,
                                              const int* __restrict__ knn,
                                              const float* __restrict__ eps_gin,
                                              float* __restrict__ h) {
  const int tid = threadIdx.x;
  const int r = blockIdx.x * 4 + (tid >> 6);   // wave per row
  const int c = tid & 63;
  const int b = r >> 12;
  const float* xfb = xf + (size_t)b * N_ * 64;
  const float eps = eps_gin[0];
  float v = (1.f + eps) * xf[(size_t)r * 64 + c];
  const int* kn = knn + r * 16;
#pragma unroll
  for (int j = 0; j < 16; ++j) {
    int m = kn[j];                              // wave-uniform scalar load
    v += xfb[(size_t)m * 64 + c];               // coalesced 256B row read
  }
  h[(size_t)r * 64 + c] = v;
}

// ---------------- K5: h1 = h @ w1 + b1, plus BN partial sums ----------------
__global__ __launch_bounds__(256) void k_gemm1(const float* __restrict__ h,
                                               const float* __restrict__ w1,
                                               const float* __restrict__ b1,
                                               float* __restrict__ h1,
                                               float* __restrict__ bn_acc) {
  __shared__ float w[64 * 64];
  __shared__ float rs[4][64], rs2[4][64];
  const int tid = threadIdx.x;
#pragma unroll
  for (int i = 0; i < 16; ++i) w[tid + i * 256] = w1[tid + i * 256];
  __syncthreads();
  const int o = tid & 63;
  const int q = tid >> 6;
  const int r0 = blockIdx.x * 64;
  const float bias = b1[o];
  float s = 0.f, s2 = 0.f;
#pragma unroll
  for (int i = 0; i < 16; ++i) {
    int row = r0 + q + i * 4;                   // wave-uniform row
    const float* hr = h + (size_t)row * 64;
    float acc = bias;
#pragma unroll
    for (int c = 0; c < 64; ++c) acc += hr[c] * w[c * 64 + o];
    h1[(size_t)row * 64 + o] = acc;
    s += acc; s2 += acc * acc;
  }
  rs[q][o] = s; rs2[q][o] = s2;
  __syncthreads();
  if (tid < 64) {
    float ts  = rs[0][tid] + rs[1][tid] + rs[2][tid] + rs[3][tid];
    float ts2 = rs2[0][tid] + rs2[1][tid] + rs2[2][tid] + rs2[3][tid];
    atomicAdd(&bn_acc[tid], ts);
    atomicAdd(&bn_acc[64 + tid], ts2);
  }
}

// ---------------- K6: finalize BN -> per-channel scale/shift ----------------
__global__ void k_bnfin(const float* __restrict__ bn_acc,
                        const float* __restrict__ gamma,
                        const float* __restrict__ beta,
                        float* __restrict__ bn_par) {
  int o = threadIdx.x;   // 64 threads
  const float inv = 1.f / (float)ROWS_;
  float mean = bn_acc[o] * inv;
  float var  = bn_acc[64 + o] * inv - mean * mean;
  float sc = gamma[o] * rsqrtf(var + 1e-5f);
  bn_par[o] = sc;
  bn_par[64 + o] = beta[o] - mean * sc;
}

// ---------------- K7: BN apply + GELU(erf) + GEMM2 + transposed store ----------------
__global__ __launch_bounds__(256) void k_final(const float* __restrict__ h1,
                                               const float* __restrict__ bn_par,
                                               const float* __restrict__ w2,
                                               const float* __restrict__ b2,
                                               float* __restrict__ out) {
  __shared__ float w[64 * 64];
  __shared__ float hg[64 * 65];                 // padded: kills stride-64 conflicts
  const int tid = threadIdx.x;
#pragma unroll
  for (int i = 0; i < 16; ++i) w[tid + i * 256] = w2[tid + i * 256];
  const int r0 = blockIdx.x * 64;
  const int b  = r0 >> 12;
  const int n0 = r0 & (N_ - 1);
  const int o = tid & 63;
  const int q = tid >> 6;
  const float sc = bn_par[o], sh = bn_par[64 + o];
#pragma unroll
  for (int i = 0; i < 16; ++i) {
    int rl = q + i * 4;
    float v = h1[(size_t)(r0 + rl) * 64 + o] * sc + sh;
    float g = 0.5f * v * (1.f + erff(v * 0.70710678118654752f));
    hg[rl * 65 + o] = g;
  }
  __syncthreads();
  const int nl = tid & 63;
#pragma unroll
  for (int i = 0; i < 16; ++i) {
    int o2 = q + i * 4;                         // wave-uniform
    float acc = b2[o2];
#pragma unroll
    for (int oo = 0; oo < 64; ++oo) acc += hg[nl * 65 + oo] * w[oo * 64 + o2];
    out[((size_t)(b * 64 + o2)) * N_ + n0 + nl] = acc;  // coalesced over n
  }
}

extern "C" void kernel_launch(void* const* d_in, const int* in_sizes, int n_in,
                              void* d_out, int out_size, void* d_ws, size_t ws_size,
                              hipStream_t stream) {
  const float* x     = (const float*)d_in[0];
  const float* w1    = (const float*)d_in[1];
  const float* b1    = (const float*)d_in[2];
  const float* gamma = (const float*)d_in[3];
  const float* beta  = (const float*)d_in[4];
  const float* w2    = (const float*)d_in[5];
  const float* b2    = (const float*)d_in[6];
  const float* eps_g = (const float*)d_in[7];
  float* out = (float*)d_out;

  char* ws = (char*)d_ws;
  float* xf   = (float*)(ws + OFF_XF);
  float* sq   = (float*)(ws + OFF_SQ);
  u32*   kd   = (u32*)  (ws + OFF_KD);
  u16*   ki   = (u16*)  (ws + OFF_KI);
  int*   knn  = (int*)  (ws + OFF_IDX);
  float* h    = (float*)(ws + OFF_H);     // aliases kd (dead after merge)
  float* h1   = (float*)(ws + OFF_H1);    // aliases kd (dead after merge)
  float* bn_acc = (float*)(ws + OFF_BN);       // aliases ki (dead after merge)
  float* bn_par = (float*)(ws + OFF_BN + 512);

  k_transpose<<<512, 256, 0, stream>>>(x, xf, sq);
  k_knn<<<1024, 256, 0, stream>>>(xf, sq, kd, ki);
  k_merge<<<ROWS_ / 256, 256, 0, stream>>>(kd, ki, knn);
  k_zero<<<1, 256, 0, stream>>>(bn_acc, 128);   // after merge: bn aliases ki
  k_aggr<<<ROWS_ / 4, 256, 0, stream>>>(xf, knn, eps_g, h);
  k_gemm1<<<ROWS_ / 64, 256, 0, stream>>>(h, w1, b1, h1, bn_acc);
  k_bnfin<<<1, 64, 0, stream>>>(bn_acc, gamma, beta, bn_par);
  k_final<<<ROWS_ / 64, 256, 0, stream>>>(h1, bn_par, w2, b2, out);
}